// Round 3
// baseline (106.047 us; speedup 1.0000x reference)
//
#include <hip/hip_runtime.h>
#include <hip/hip_bf16.h>

typedef __hip_bfloat16 bf16;
typedef float f32x4 __attribute__((ext_vector_type(4)));
typedef short bf16x8 __attribute__((ext_vector_type(8)));   // 8 bf16 in 4 VGPRs
typedef int   int4v  __attribute__((ext_vector_type(4)));

constexpr int Bb = 2, Ss = 2048, Dd = 1024, Hh = 16, Ww = 128, HDd = 64;
constexpr int Mrows = Bb * Ss;   // 4096
constexpr int NT = Dd / 64;      // 16 K-tiles of BK=64

// async global->LDS, 16B per lane; HW dest = readfirstlane(base) + lane*16
__device__ __forceinline__ void gload16(const void* g, void* l) {
  __builtin_amdgcn_global_load_lds(
      (const __attribute__((address_space(1))) void*)g,
      (__attribute__((address_space(3))) void*)l, 16, 0, 0);
}

// ---------------------------------------------------------------- conversions
__global__ __launch_bounds__(256) void convert_bf16_k(const float* __restrict__ in,
                                                      bf16* __restrict__ out) {
  size_t i = (size_t)blockIdx.x * 256 + threadIdx.x;
  float4 v = reinterpret_cast<const float4*>(in)[i];
  union { bf16 b[4]; ushort4 u; } cv;
  cv.b[0] = __float2bfloat16(v.x);
  cv.b[1] = __float2bfloat16(v.y);
  cv.b[2] = __float2bfloat16(v.z);
  cv.b[3] = __float2bfloat16(v.w);
  reinterpret_cast<ushort4*>(out)[i] = cv.u;
}

// 4 weights [K][N] fp32 -> contiguous bf16 [4][N][K] (B^T form)
__global__ __launch_bounds__(256) void transpose_w4_k(const float* __restrict__ W0,
                                                      const float* __restrict__ W1,
                                                      const float* __restrict__ W2,
                                                      const float* __restrict__ W3,
                                                      bf16* __restrict__ out) {
  const float* Win = (blockIdx.z == 0) ? W0 : (blockIdx.z == 1) ? W1
                     : (blockIdx.z == 2) ? W2 : W3;
  bf16* o = out + (size_t)blockIdx.z * Dd * Dd;
  __shared__ float tile[32][33];
  int bx = blockIdx.x, by = blockIdx.y;
  int tx = threadIdx.x & 31, ty = threadIdx.x >> 5;
#pragma unroll
  for (int i = 0; i < 4; ++i)
    tile[ty + i * 8][tx] = Win[(size_t)(by * 32 + ty + i * 8) * Dd + bx * 32 + tx];
  __syncthreads();
#pragma unroll
  for (int i = 0; i < 4; ++i)
    o[(size_t)(bx * 32 + ty + i * 8) * Dd + by * 32 + tx] =
        __float2bfloat16(tile[tx][ty + i * 8]);
}

// ---------------------------------------------------------------- QKV: 256x256 8-phase GEMM
// A: [4096][1024] bf16.  Wt3: [3072][1024] bf16 (B^T).  BK=64, 8 waves.
// LDS byte map (131072): buf b: A-half h at b*65536 + h*16384 ;  B-half h at +32768.
// Swizzle: logical (row, chunk lc of 8x16B) stored at physical chunk lc ^ (row&7).

#define STAGE_A(BUF, HALF, KT)                                                   \
  { _Pragma("unroll")                                                            \
    for (int i_ = 0; i_ < 2; ++i_) {                                             \
      int ci_ = i_ * 512 + w * 64 + lane;                                        \
      int row_ = ci_ >> 3, pc_ = ci_ & 7, lc_ = pc_ ^ (row_ & 7);                \
      gload16(Apan + (size_t)((HALF) * 128 + row_) * Dd + (KT) * 64 + lc_ * 8,   \
              ldsB + (BUF) * 65536 + (HALF) * 16384 + ci_ * 16);                 \
    } }

#define STAGE_B(BUF, HALF, KT)                                                   \
  { _Pragma("unroll")                                                            \
    for (int i_ = 0; i_ < 2; ++i_) {                                             \
      int ci_ = i_ * 512 + w * 64 + lane;                                        \
      int row_ = ci_ >> 3, pc_ = ci_ & 7, lc_ = pc_ ^ (row_ & 7);                \
      gload16(Bpan + (size_t)((HALF) * 128 + row_) * Dd + (KT) * 64 + lc_ * 8,   \
              ldsB + (BUF) * 65536 + 32768 + (HALF) * 16384 + ci_ * 16);         \
    } }

#define QPH(QD, BUF, STAGE_STMT, LAST)                                           \
  {                                                                              \
    bf16x8 a00, a01, a10, a11;                                                   \
    { int r0_ = ((QD) * 2 + 0) * 16 + l15, r1_ = ((QD) * 2 + 1) * 16 + l15;      \
      const char* ab_ = ldsB + (BUF) * 65536 + wr * 16384;                       \
      a00 = *(const bf16x8*)(ab_ + r0_ * 128 + ((0 + l16) ^ (r0_ & 7)) * 16);    \
      a01 = *(const bf16x8*)(ab_ + r0_ * 128 + ((4 + l16) ^ (r0_ & 7)) * 16);    \
      a10 = *(const bf16x8*)(ab_ + r1_ * 128 + ((0 + l16) ^ (r1_ & 7)) * 16);    \
      a11 = *(const bf16x8*)(ab_ + r1_ * 128 + ((4 + l16) ^ (r1_ & 7)) * 16); }  \
    STAGE_STMT;                                                                  \
    __builtin_amdgcn_s_barrier();                                                \
    __builtin_amdgcn_s_setprio(1);                                               \
    _Pragma("unroll")                                                            \
    for (int nf = 0; nf < 4; ++nf) {                                             \
      acc[(QD)*2+0][nf] = __builtin_amdgcn_mfma_f32_16x16x32_bf16(a00, bfr[nf][0], acc[(QD)*2+0][nf], 0, 0, 0); \
      acc[(QD)*2+0][nf] = __builtin_amdgcn_mfma_f32_16x16x32_bf16(a01, bfr[nf][1], acc[(QD)*2+0][nf], 0, 0, 0); \
      acc[(QD)*2+1][nf] = __builtin_amdgcn_mfma_f32_16x16x32_bf16(a10, bfr[nf][0], acc[(QD)*2+1][nf], 0, 0, 0); \
      acc[(QD)*2+1][nf] = __builtin_amdgcn_mfma_f32_16x16x32_bf16(a11, bfr[nf][1], acc[(QD)*2+1][nf], 0, 0, 0); \
    }                                                                            \
    __builtin_amdgcn_s_setprio(0);                                               \
    __builtin_amdgcn_sched_barrier(0);                                           \
    if (LAST) { asm volatile("s_waitcnt vmcnt(4)" ::: "memory"); }               \
    __builtin_amdgcn_s_barrier();                                                \
  }

#define TILE(KT, BUF)                                                            \
  {                                                                              \
    bf16x8 bfr[4][2];                                                            \
    _Pragma("unroll")                                                            \
    for (int nf = 0; nf < 4; ++nf) {                                             \
      int rn_ = (wn & 1) * 64 + nf * 16 + l15;                                   \
      const char* bb_ = ldsB + (BUF) * 65536 + 32768 + (wn >> 1) * 16384;        \
      bfr[nf][0] = *(const bf16x8*)(bb_ + rn_ * 128 + ((0 + l16) ^ (rn_ & 7)) * 16); \
      bfr[nf][1] = *(const bf16x8*)(bb_ + rn_ * 128 + ((4 + l16) ^ (rn_ & 7)) * 16); \
    }                                                                            \
    QPH(0, BUF, if ((KT) + 1 < NT) STAGE_A((BUF) ^ 1, 0, (KT) + 1), false)       \
    QPH(1, BUF, if ((KT) + 1 < NT) STAGE_A((BUF) ^ 1, 1, (KT) + 1), false)       \
    QPH(2, BUF, if ((KT) + 2 < NT) STAGE_B((BUF), 0, (KT) + 2), false)           \
    QPH(3, BUF, if ((KT) + 2 < NT) STAGE_B((BUF), 1, (KT) + 2), true)            \
  }

__global__ __launch_bounds__(512, 2) void gemm_qkv8(const bf16* __restrict__ A,
                                                    const bf16* __restrict__ Wt3,
                                                    const float* __restrict__ bq,
                                                    const float* __restrict__ bk,
                                                    const float* __restrict__ bv,
                                                    bf16* __restrict__ Qh,
                                                    bf16* __restrict__ Kh,
                                                    bf16* __restrict__ Vt) {
  __shared__ __align__(16) char ldsbuf[131072];
  char* ldsB = ldsbuf;
  const int t = threadIdx.x, lane = t & 63, w = t >> 6;
  const int wr = w >> 2, wn = w & 3;           // 2 x 4 wave grid
  const int l15 = lane & 15, l16 = lane >> 4;

  // XCD-bijective swizzle: 192 blocks, 192 % 8 == 0
  int orig = blockIdx.x;
  int wg = (orig & 7) * 24 + (orig >> 3);
  int bm = wg / 12, bn = wg % 12;

  const bf16* Apan = A + (size_t)bm * 256 * Dd;
  const bf16* Bpan = Wt3 + (size_t)bn * 256 * Dd;

  f32x4 acc[8][4] = {};

  // prologue: tile0 A+B, tile1 B  (12 loads/wave); tile0 guaranteed landed
  STAGE_A(0, 0, 0)
  STAGE_A(0, 1, 0)
  STAGE_B(0, 0, 0)
  STAGE_B(0, 1, 0)
  STAGE_B(1, 0, 1)
  STAGE_B(1, 1, 1)
  asm volatile("s_waitcnt vmcnt(4)" ::: "memory");
  __builtin_amdgcn_s_barrier();

  for (int kt = 0; kt < NT; kt += 2) {
    TILE(kt, 0)
    TILE(kt + 1, 1)
  }

  // epilogue: rows bm*256 + wr*128 + mf*16 + l16*4 + r ; cols bn*256 + wn*64 + nf*16 + l15
#pragma unroll
  for (int nf = 0; nf < 4; ++nf) {
    int colg = bn * 256 + wn * 64 + nf * 16 + l15;   // 0..3071
    int p = colg >> 10, c = colg & 1023;
    int h = c >> 6, hd = c & (HDd - 1);
    const float* bp = (p == 0) ? bq : (p == 1) ? bk : bv;
    float bi = bp[c];
#pragma unroll
    for (int mf = 0; mf < 8; ++mf) {
      int s0 = bm * 256 + wr * 128 + mf * 16 + l16 * 4;
      int b = s0 >> 11, s = s0 & (Ss - 1);
      if (p < 2) {
        bf16* o = p ? Kh : Qh;
        size_t base = (((size_t)(b * Hh + h)) * Ss + s) * HDd + hd;
#pragma unroll
        for (int r = 0; r < 4; ++r)
          o[base + (size_t)r * HDd] = __float2bfloat16(acc[mf][nf][r] + bi);
      } else {
        union { ushort4 u; ushort e[4]; } pk;
#pragma unroll
        for (int r = 0; r < 4; ++r) {
          bf16 tb = __float2bfloat16(acc[mf][nf][r] + bi);
          pk.e[r] = *reinterpret_cast<ushort*>(&tb);
        }
        *reinterpret_cast<ushort4*>(&Vt[(((size_t)(b * Hh + h)) * HDd + hd) * Ss + s]) = pk.u;
      }
    }
  }
}

// ---------------------------------------------------------------- O-proj (m97 128^2 structure)
__device__ __forceinline__ void gemm_core(const bf16* __restrict__ A,
                                          const bf16* __restrict__ Bt,
                                          int bm, int bn,
                                          bf16* As, bf16* Bs, f32x4 acc[4][4]) {
  const int t = threadIdx.x;
  const int lane = t & 63, w = t >> 6;
  const int wr = w >> 1, wc = w & 1;
  const int l15 = lane & 15, l16 = lane >> 4;
  const bf16* Arow0 = A + (size_t)bm * 128 * Dd;
  const bf16* Brow0 = Bt + (size_t)bn * 128 * Dd;

  for (int kt = 0; kt < Dd / 32; ++kt) {
    __syncthreads();
#pragma unroll
    for (int i = 0; i < 2; ++i) {
      int chunk = i * 256 + t;
      int row = chunk >> 2, c8 = (chunk & 3) * 8;
      gload16(Arow0 + (size_t)row * Dd + kt * 32 + c8, As + chunk * 8);
      gload16(Brow0 + (size_t)row * Dd + kt * 32 + c8, Bs + chunk * 8);
    }
    __syncthreads();
    bf16x8 af[4], bfr[4];
#pragma unroll
    for (int m = 0; m < 4; ++m)
      af[m] = *reinterpret_cast<const bf16x8*>(As + (wr * 64 + m * 16 + l15) * 32 + l16 * 8);
#pragma unroll
    for (int n = 0; n < 4; ++n)
      bfr[n] = *reinterpret_cast<const bf16x8*>(Bs + (wc * 64 + n * 16 + l15) * 32 + l16 * 8);
#pragma unroll
    for (int m = 0; m < 4; ++m)
#pragma unroll
      for (int n = 0; n < 4; ++n)
        acc[m][n] = __builtin_amdgcn_mfma_f32_16x16x32_bf16(af[m], bfr[n], acc[m][n], 0, 0, 0);
  }
}

__global__ __launch_bounds__(256) void gemm_o(const bf16* __restrict__ A,
                                              const bf16* __restrict__ Wt,
                                              const float* __restrict__ bias,
                                              const float* __restrict__ resid,
                                              float* __restrict__ out) {
  __shared__ bf16 As[128 * 32], Bs[128 * 32];
  f32x4 acc[4][4] = {};
  const int bm = blockIdx.y, bn = blockIdx.x;
  gemm_core(A, Wt, bm, bn, As, Bs, acc);

  const int lane = threadIdx.x & 63, w = threadIdx.x >> 6;
  const int wr = w >> 1, wc = w & 1, l15 = lane & 15, l16 = lane >> 4;
#pragma unroll
  for (int m = 0; m < 4; ++m) {
    int row_l = wr * 64 + m * 16 + l16 * 4;
#pragma unroll
    for (int n = 0; n < 4; ++n) {
      int col = bn * 128 + wc * 64 + n * 16 + l15;
      float bi = bias[col];
#pragma unroll
      for (int r = 0; r < 4; ++r) {
        int row = bm * 128 + row_l + r;
        size_t idx = (size_t)row * Dd + col;
        out[idx] = acc[m][n][r] + bi + resid[idx];
      }
    }
  }
}

// ---------------------------------------------------------------- local attention
__global__ __launch_bounds__(256) void attn_local(const bf16* __restrict__ Q,
                                                  const bf16* __restrict__ K,
                                                  const bf16* __restrict__ Vt,
                                                  bf16* __restrict__ AO) {
  __shared__ bf16 Ps[4][16][200];
  const int t = threadIdx.x, lane = t & 63, w = t >> 6;
  const int l15 = lane & 15, l16 = lane >> 4;
  const int qb = blockIdx.x, h = blockIdx.y, b = blockIdx.z;
  const int q0 = qb * 64, kstart = q0 - 128;
  const bf16* Qp = Q + ((size_t)(b * Hh + h)) * Ss * HDd;
  const bf16* Kp = K + ((size_t)(b * Hh + h)) * Ss * HDd;
  const bf16* Vp = Vt + ((size_t)(b * Hh + h)) * HDd * Ss;

  const int qrow = q0 + w * 16 + l15;
  bf16x8 aq0 = *reinterpret_cast<const bf16x8*>(Qp + (size_t)qrow * HDd + l16 * 8);
  bf16x8 aq1 = *reinterpret_cast<const bf16x8*>(Qp + (size_t)qrow * HDd + 32 + l16 * 8);

  f32x4 sc[9];
#pragma unroll
  for (int j = 0; j < 9; ++j) {
    int key = kstart + (w + j) * 16 + l15;
    int kc = key < 0 ? 0 : key;
    bf16x8 bk0 = *reinterpret_cast<const bf16x8*>(Kp + (size_t)kc * HDd + l16 * 8);
    bf16x8 bk1 = *reinterpret_cast<const bf16x8*>(Kp + (size_t)kc * HDd + 32 + l16 * 8);
    f32x4 s = {};
    s = __builtin_amdgcn_mfma_f32_16x16x32_bf16(aq0, bk0, s, 0, 0, 0);
    s = __builtin_amdgcn_mfma_f32_16x16x32_bf16(aq1, bk1, s, 0, 0, 0);
    sc[j] = s;
  }

  const float scale = 0.125f;
  float mrow[4], ssum[4], inv[4];
  int qg[4];
#pragma unroll
  for (int r = 0; r < 4; ++r) { mrow[r] = -1e30f; qg[r] = q0 + w * 16 + l16 * 4 + r; }
#pragma unroll
  for (int j = 0; j < 9; ++j) {
    int kg = kstart + (w + j) * 16 + l15;
#pragma unroll
    for (int r = 0; r < 4; ++r) {
      bool valid = (kg >= 0) && (kg <= qg[r]) && (qg[r] - kg < Ww);
      float v = valid ? sc[j][r] * scale : -1e9f;
      sc[j][r] = v;
      mrow[r] = fmaxf(mrow[r], v);
    }
  }
#pragma unroll
  for (int r = 0; r < 4; ++r)
#pragma unroll
    for (int off = 1; off < 16; off <<= 1)
      mrow[r] = fmaxf(mrow[r], __shfl_xor(mrow[r], off));
#pragma unroll
  for (int r = 0; r < 4; ++r) ssum[r] = 0.f;
#pragma unroll
  for (int j = 0; j < 9; ++j)
#pragma unroll
    for (int r = 0; r < 4; ++r) {
      float p = __expf(sc[j][r] - mrow[r]);
      sc[j][r] = p;
      ssum[r] += p;
    }
#pragma unroll
  for (int r = 0; r < 4; ++r)
#pragma unroll
    for (int off = 1; off < 16; off <<= 1)
      ssum[r] += __shfl_xor(ssum[r], off);
#pragma unroll
  for (int r = 0; r < 4; ++r) inv[r] = 1.f / ssum[r];

#pragma unroll
  for (int j = 0; j < 9; ++j)
#pragma unroll
    for (int r = 0; r < 4; ++r)
      Ps[w][l16 * 4 + r][(w + j) * 16 + l15] = __float2bfloat16(sc[j][r]);
  {
    int ktz = (w & 1) ? (w - 1) : (w + 9);
    bf16 z16 = __float2bfloat16(0.f);
#pragma unroll
    for (int r = 0; r < 4; ++r)
      Ps[w][l16 * 4 + r][ktz * 16 + l15] = z16;
  }

  const int c0 = w >> 1;
  f32x4 o[4] = {};
#pragma unroll
  for (int cc = 0; cc < 5; ++cc) {
    int c = c0 + cc;
    bf16x8 pf = *reinterpret_cast<const bf16x8*>(&Ps[w][l15][c * 32 + l16 * 8]);
    int kk = kstart + c * 32 + l16 * 8;
    int kc = kk < 0 ? 0 : kk;
#pragma unroll
    for (int ht = 0; ht < 4; ++ht) {
      bf16x8 vf = *reinterpret_cast<const bf16x8*>(Vp + (size_t)(ht * 16 + l15) * Ss + kc);
      o[ht] = __builtin_amdgcn_mfma_f32_16x16x32_bf16(pf, vf, o[ht], 0, 0, 0);
    }
  }

#pragma unroll
  for (int ht = 0; ht < 4; ++ht)
#pragma unroll
    for (int r = 0; r < 4; ++r) {
      int qw = q0 + w * 16 + l16 * 4 + r;
      int col = h * HDd + ht * 16 + l15;
      AO[(size_t)(b * Ss + qw) * Dd + col] = __float2bfloat16(o[ht][r] * inv[r]);
    }
}

// ---------------------------------------------------------------- LayerNorm (in-place)
__global__ __launch_bounds__(256) void ln_inplace(float* __restrict__ y,
                                                  const float* __restrict__ gamma,
                                                  const float* __restrict__ beta) {
  int row = blockIdx.x;
  float* yr = y + (size_t)row * Dd;
  float4 v = reinterpret_cast<const float4*>(yr)[threadIdx.x];
  float s = v.x + v.y + v.z + v.w;
  float s2 = v.x * v.x + v.y * v.y + v.z * v.z + v.w * v.w;
#pragma unroll
  for (int off = 1; off < 64; off <<= 1) {
    s += __shfl_xor(s, off);
    s2 += __shfl_xor(s2, off);
  }
  __shared__ float r1[4], r2[4];
  int w = threadIdx.x >> 6;
  if ((threadIdx.x & 63) == 0) { r1[w] = s; r2[w] = s2; }
  __syncthreads();
  s = r1[0] + r1[1] + r1[2] + r1[3];
  s2 = r2[0] + r2[1] + r2[2] + r2[3];
  float mu = s * (1.f / Dd);
  float var = s2 * (1.f / Dd) - mu * mu;
  float rs = rsqrtf(var + 1e-5f);
  float4 g = reinterpret_cast<const float4*>(gamma)[threadIdx.x];
  float4 be = reinterpret_cast<const float4*>(beta)[threadIdx.x];
  float4 o;
  o.x = (v.x - mu) * rs * g.x + be.x;
  o.y = (v.y - mu) * rs * g.y + be.y;
  o.z = (v.z - mu) * rs * g.z + be.z;
  o.w = (v.w - mu) * rs * g.w + be.w;
  reinterpret_cast<float4*>(yr)[threadIdx.x] = o;
}

// ---------------------------------------------------------------- launch
extern "C" void kernel_launch(void* const* d_in, const int* in_sizes, int n_in,
                              void* d_out, int out_size, void* d_ws, size_t ws_size,
                              hipStream_t stream) {
  const float* x     = (const float*)d_in[0];
  const float* Wq    = (const float*)d_in[1];
  const float* bq    = (const float*)d_in[2];
  const float* Wk    = (const float*)d_in[3];
  const float* bk    = (const float*)d_in[4];
  const float* Wv    = (const float*)d_in[5];
  const float* bv    = (const float*)d_in[6];
  const float* Wo    = (const float*)d_in[7];
  const float* bo    = (const float*)d_in[8];
  const float* gamma = (const float*)d_in[9];
  const float* beta  = (const float*)d_in[10];
  float* out = (float*)d_out;

  char* ws = (char*)d_ws;
  bf16* xb  = (bf16*)(ws + (size_t)0);          // 8 MB
  bf16* WtQ = (bf16*)(ws + ((size_t)8  << 20)); // 2 MB each; Q,K,V contiguous
  bf16* WtO = (bf16*)(ws + ((size_t)14 << 20));
  bf16* Qh  = (bf16*)(ws + ((size_t)16 << 20)); // [b][h][s][hd]
  bf16* Kh  = (bf16*)(ws + ((size_t)24 << 20)); // [b][h][s][hd]
  bf16* Vt  = (bf16*)(ws + ((size_t)32 << 20)); // [b][h][hd][s]
  bf16* AO  = (bf16*)(ws + ((size_t)40 << 20)); // [b][s][d]

  convert_bf16_k<<<Mrows * Dd / (256 * 4), 256, 0, stream>>>(x, xb);
  transpose_w4_k<<<dim3(32, 32, 4), 256, 0, stream>>>(Wq, Wk, Wv, Wo, WtQ);

  gemm_qkv8<<<192, 512, 0, stream>>>(xb, WtQ, bq, bk, bv, Qh, Kh, Vt);

  attn_local<<<dim3(Ss / 64, Hh, Bb), 256, 0, stream>>>(Qh, Kh, Vt, AO);

  gemm_o<<<dim3(8, 32), 256, 0, stream>>>(AO, WtO, bo, x, out);
  ln_inplace<<<Mrows, 256, 0, stream>>>(out, gamma, beta);
}